// Round 5
// baseline (1321.486 us; speedup 1.0000x reference)
//
#include <hip/hip_runtime.h>
#include <stdint.h>
#include <math.h>

// Problem constants (fixed by reference setup_inputs)
#define B_SZ   32
#define T_LEN  2048
#define DIN    512
#define DD     512
#define M_TOT  (B_SZ * T_LEN)   // 65536 rows
#define BM     64               // fused-kernel row tile
#define WSZ    ((size_t)DD * DD)

typedef unsigned short u16;
typedef __attribute__((ext_vector_type(8))) short short8;
typedef __attribute__((ext_vector_type(4))) float f32x4;
typedef __attribute__((ext_vector_type(4))) unsigned int u32x4;

// ---------------------------------------------------------------------------
// fp32 -> bf16 round-to-nearest-even (scalar, for wt_all)
// ---------------------------------------------------------------------------
__device__ __forceinline__ u16 f2bf(float f) {
  uint32_t u = __float_as_uint(f);
  uint32_t r = (u + 0x7FFFu + ((u >> 16) & 1u)) >> 16;
  return (u16)r;
}

// packed f32x2 -> bf16x2 (RTNE), gfx950 hw instruction (no builtin)
__device__ __forceinline__ uint32_t cvtpk(float lo, float hi) {
  uint32_t r;
  asm("v_cvt_pk_bf16_f32 %0, %1, %2" : "=v"(r) : "v"(lo), "v"(hi));
  return r;
}

// async global->LDS, 16B per lane
typedef const void __attribute__((address_space(1)))* as1cp;
typedef void __attribute__((address_space(3)))* as3p;
__device__ __forceinline__ void async16(const void* g, void* l) {
  __builtin_amdgcn_global_load_lds((as1cp)(uintptr_t)g,
                                   (as3p)(uint32_t)(uintptr_t)l, 16, 0, 0);
}

__device__ __forceinline__ float sigm_fast(float x) {
  return 1.f / (1.f + __expf(-x));
}
__device__ __forceinline__ float tanh_fast(float x) {
  return 1.f - 2.f / (1.f + __expf(2.f * x));
}

// ---------------------------------------------------------------------------
// Threefry-2x32 (20 rounds), bit-exact vs JAX's threefry2x32 primitive.
// ---------------------------------------------------------------------------
__device__ __forceinline__ uint32_t rotl32(uint32_t x, int n) {
  return (x << n) | (x >> (32 - n));
}

__device__ __forceinline__ void threefry2x32(uint32_t k0, uint32_t k1,
                                             uint32_t x0, uint32_t x1,
                                             uint32_t& o0, uint32_t& o1) {
  const uint32_t ks0 = k0, ks1 = k1, ks2 = k0 ^ k1 ^ 0x1BD11BDAu;
  uint32_t v0 = x0 + ks0, v1 = x1 + ks1;
#define TF_R(r) { v0 += v1; v1 = rotl32(v1, (r)); v1 ^= v0; }
  TF_R(13) TF_R(15) TF_R(26) TF_R(6)
  v0 += ks1; v1 += ks2 + 1u;
  TF_R(17) TF_R(29) TF_R(16) TF_R(24)
  v0 += ks2; v1 += ks0 + 2u;
  TF_R(13) TF_R(15) TF_R(26) TF_R(6)
  v0 += ks0; v1 += ks1 + 3u;
  TF_R(17) TF_R(29) TF_R(16) TF_R(24)
  v0 += ks1; v1 += ks2 + 4u;
  TF_R(13) TF_R(15) TF_R(26) TF_R(6)
  v0 += ks2; v1 += ks0 + 5u;
#undef TF_R
  o0 = v0; o1 = v1;
}

// ---------------------------------------------------------------------------
// Noise under JAX_ENABLE_X64=1 + partitionable threefry (verified round 3):
//   split (foldlike): keys[j] = threefry(key, (0, j))
//   bernoulli(p: python float -> f64): 64-bit draw bits64[i]=(b1<<32)|b2,
//   counter (0,i); u<0.25 <=> b1<0x40000000 ; u<0.75 <=> b1<0xC0000000
// ---------------------------------------------------------------------------
__global__ void noise_kernel(float* __restrict__ noise_i, float* __restrict__ noise_s) {
  int i = blockIdx.x * blockDim.x + threadIdx.x;
  if (i >= B_SZ * DIN) return;
  uint32_t k1a, k1b, k2a, k2b;
  threefry2x32(0u, 42u, 0u, 0u, k1a, k1b);
  threefry2x32(0u, 42u, 0u, 1u, k2a, k2b);
  uint32_t b1, b2;
  threefry2x32(k1a, k1b, 0u, (uint32_t)i, b1, b2);
  noise_i[i] = (b1 < 0x40000000u) ? 4.0f : 0.0f;
  threefry2x32(k2a, k2b, 0u, (uint32_t)i, b1, b2);
  noise_s[i] = (b1 < 0xC0000000u) ? (1.0f / 0.75f) : 0.0f;
}

// layer-0 state projections, exact fp32 (t-independent)
__global__ __launch_bounds__(256) void vec0_kernel(
    const float* __restrict__ h0, const float* __restrict__ noise_s,
    const float* __restrict__ rHw, const float* __restrict__ rHb,
    const float* __restrict__ rTw, const float* __restrict__ rTb,
    float* __restrict__ vH0, float* __restrict__ vT0) {
  __shared__ float sdv[DD];
  const int b = blockIdx.x >> 1;
  const int c = (blockIdx.x & 1) * 256 + threadIdx.x;
  for (int k = threadIdx.x; k < DD; k += 256)
    sdv[k] = h0[k] * noise_s[b * DD + k];
  __syncthreads();
  float aH = 0.f, aT = 0.f;
  for (int k = 0; k < DD; ++k) {
    float v = sdv[k];
    aH += v * rHw[(size_t)k * DD + c];
    aT += v * rTw[(size_t)k * DD + c];
  }
  vH0[b * DD + c] = aH + rHb[c];
  vT0[b * DD + c] = aT + rTb[c];
}

// ---------------------------------------------------------------------------
// Transpose+convert all six 512x512 fp32 W[k][n] -> bf16 Wt[n][k].
// Wt order: 0=wH 1=wT 2=r1H 3=r1T 4=r2H 5=r2T
// ---------------------------------------------------------------------------
__global__ __launch_bounds__(256) void wt_all(
    const float* __restrict__ wH, const float* __restrict__ wT,
    const float* __restrict__ rHw, const float* __restrict__ rTw,
    u16* __restrict__ Wt) {
  __shared__ float tile[64][68];
  const int which = blockIdx.x >> 6;
  const float* W;
  switch (which) {
    case 0: W = wH; break;
    case 1: W = wT; break;
    case 2: W = rHw + WSZ; break;
    case 3: W = rTw + WSZ; break;
    case 4: W = rHw + 2 * WSZ; break;
    default: W = rTw + 2 * WSZ; break;
  }
  u16* dst = Wt + (size_t)which * WSZ;
  const int tb = blockIdx.x & 63;
  const int kt = (tb >> 3) * 64;
  const int nt = (tb & 7) * 64;
  const int tid = threadIdx.x;
  {
    int r = tid >> 2;
#pragma unroll
    for (int u = 0; u < 4; ++u) {
      int c = ((tid & 3) + u * 4) * 4;
      float4 v = *(const float4*)(W + (size_t)(kt + r) * DD + nt + c);
      tile[r][c] = v.x; tile[r][c + 1] = v.y; tile[r][c + 2] = v.z; tile[r][c + 3] = v.w;
    }
  }
  __syncthreads();
  {
    int n = tid >> 2, seg = (tid & 3) * 16;
    u16 o[16];
#pragma unroll
    for (int u = 0; u < 16; ++u) o[u] = f2bf(tile[seg + u][n]);
    *(uint4*)(dst + (size_t)(nt + n) * DD + kt + seg) = *(const uint4*)o;
    *(uint4*)(dst + (size_t)(nt + n) * DD + kt + seg + 8) = *(const uint4*)(o + 8);
  }
}

// ---------------------------------------------------------------------------
// FUSED 3-LAYER RHN kernel.
// Block: 64 rows x full 512 cols; 512 threads = 8 waves, wave w owns cols
// [64w, 64w+64). State tile S (f32, XOR-swizzled) lives in LDS for the whole
// depth; layers never round-trip through HBM. W (bf16, [n][k]) streams from
// global straight into registers (ping-pong prefetch, NO barriers in K-loop;
// waves run decoupled). A-fragments are built per chunk from S * noise and
// packed to bf16 with v_cvt_pk_bf16_f32.
//   Swizzle: byte(row,k) = row*2048 + ((k*4) ^ ((row&7)<<4))  [16B slots]
//   -> quarter-wave frag reads hit 8 distinct 16B slots (2-way = free).
//   Layer-0 staging: linear LDS dest + inverse-swizzled GLOBAL source.
// Epilogue per layer: highway combine in f32, S updated in-place (same
// thread r/w), only layer 2 writes to global out.
// ---------------------------------------------------------------------------
__global__ __launch_bounds__(512, 2) void fused_rhn(
    const float* __restrict__ seq,   // [65536][512] f32
    const u16* __restrict__ Wt,      // 6 x [512n][512k] bf16
    const float* __restrict__ noise_i,  // [32][512]
    const float* __restrict__ noise_s,  // [32][512]
    const float* __restrict__ vH0,   // [32][512]
    const float* __restrict__ vT0,
    const float* __restrict__ h0,    // [512]
    const float* __restrict__ bH, const float* __restrict__ bT,
    const float* __restrict__ rHb, const float* __restrict__ rTb,
    float* __restrict__ out) {
  __shared__ float S[BM * DD];       // 128 KB, swizzled f32 state tile
  __shared__ float nzi[DD];
  __shared__ float nzs[DD];

  const int tid  = threadIdx.x;      // 0..511
  const int lane = tid & 63, wid = tid >> 6;
  const int m0   = blockIdx.x * BM;
  const int bidx = m0 >> 11;         // batch index (64 | 2048)
  const int q  = lane >> 4, mr = lane & 15;
  const int c0w = wid * 64;          // wave's column base
  const int swm = (mr & 7) << 4;     // frag-read swizzle (row&7 == mr&7)

  // stage noise rows for this batch
  if (tid < DD) {
    nzi[tid] = noise_i[bidx * DD + tid];
    nzs[tid] = noise_s[bidx * DD + tid];
  }
  // stage seq tile as layer-0 A/state: linear LDS dest, pre-swizzled source.
  // granule g: row = g>>7, slot = g&127 holds source k16 = slot ^ (row&7).
#pragma unroll
  for (int t = 0; t < 16; ++t) {
    int g = tid + t * 512;
    int row = g >> 7, slot = g & 127;
    int j16 = slot ^ (row & 7);
    async16(seq + (size_t)(m0 + row) * DD + j16 * 4, (char*)S + (size_t)g * 16);
  }
  __syncthreads();   // drains vmcnt (compiler emits vmcnt(0) before barrier)

  for (int l = 0; l < 3; ++l) {
    const u16* WH = Wt + (size_t)(2 * l) * WSZ;
    const u16* WTm = WH + WSZ;
    const float* nz = (l == 0) ? nzi : nzs;

    f32x4 accH[4][4], accT[4][4];
#pragma unroll
    for (int i = 0; i < 4; ++i)
#pragma unroll
      for (int j = 0; j < 4; ++j) {
        accH[i][j] = (f32x4){0.f, 0.f, 0.f, 0.f};
        accT[i][j] = (f32x4){0.f, 0.f, 0.f, 0.f};
      }

    // W fragment ping-pong: bank holds 4 H-frags + 4 T-frags (16B each)
    short8 wh[2][4], wt_[2][4];
#pragma unroll
    for (int nt = 0; nt < 4; ++nt) {
      const size_t co = (size_t)(c0w + nt * 16 + mr) * DD + q * 8;
      wh[0][nt]  = *(const short8*)(WH + co);
      wt_[0][nt] = *(const short8*)(WTm + co);
    }

#pragma unroll
    for (int kb = 0; kb < 16; ++kb) {
      const int cur = kb & 1, nxt = cur ^ 1;
      if (kb < 15) {
#pragma unroll
        for (int nt = 0; nt < 4; ++nt) {
          const size_t co = (size_t)(c0w + nt * 16 + mr) * DD + (kb + 1) * 32 + q * 8;
          wh[nxt][nt]  = *(const short8*)(WH + co);
          wt_[nxt][nt] = *(const short8*)(WTm + co);
        }
      }
      // noise slice for k = kb*32 + q*8 .. +8 (uniform per quarter-wave)
      const int k0 = kb * 32 + q * 8;
      const float4 n0 = *(const float4*)&nz[k0];
      const float4 n1 = *(const float4*)&nz[k0 + 4];
      // A-frags: rows mt*16+mr, k-slice; swizzled S reads + pack to bf16
      short8 a[4];
#pragma unroll
      for (int mt = 0; mt < 4; ++mt) {
        const int row = mt * 16 + mr;
        const char* Sb = (const char*)S + (size_t)row * 2048;
        const int kbase = kb * 128 + q * 32;
        float4 v0 = *(const float4*)(Sb + (kbase ^ swm));
        float4 v1 = *(const float4*)(Sb + ((kbase + 16) ^ swm));
        u32x4 pk;
        pk.x = cvtpk(v0.x * n0.x, v0.y * n0.y);
        pk.y = cvtpk(v0.z * n0.z, v0.w * n0.w);
        pk.z = cvtpk(v1.x * n1.x, v1.y * n1.y);
        pk.w = cvtpk(v1.z * n1.z, v1.w * n1.w);
        a[mt] = *(short8*)&pk;
      }
#pragma unroll
      for (int nt = 0; nt < 4; ++nt) {
#pragma unroll
        for (int mt = 0; mt < 4; ++mt) {
          accH[mt][nt] = __builtin_amdgcn_mfma_f32_16x16x32_bf16(a[mt], wh[cur][nt],  accH[mt][nt], 0, 0, 0);
          accT[mt][nt] = __builtin_amdgcn_mfma_f32_16x16x32_bf16(a[mt], wt_[cur][nt], accT[mt][nt], 0, 0, 0);
        }
      }
    }

    // all waves done reading S before we overwrite it
    __syncthreads();

    const float* hbv = (l == 0) ? bH : (rHb + l * DD);
    const float* tbv = (l == 0) ? bT : (rTb + l * DD);
    const int b512 = bidx * DD;
#pragma unroll
    for (int nt = 0; nt < 4; ++nt) {
      const int gc = c0w + nt * 16 + mr;
      float hb = hbv[gc], tb = tbv[gc];
      float h0c = 0.f;
      if (l == 0) {
        hb += vH0[b512 + gc];
        tb += vT0[b512 + gc];
        h0c = h0[gc];
      }
#pragma unroll
      for (int mt = 0; mt < 4; ++mt) {
#pragma unroll
        for (int r = 0; r < 4; ++r) {
          const int row = mt * 16 + q * 4 + r;
          char* Sp = (char*)S + (size_t)row * 2048 + (((unsigned)(gc * 4)) ^ ((row & 7) << 4));
          float sp = (l == 0) ? h0c : *(const float*)Sp;
          float hg = tanh_fast(accH[mt][nt][r] + hb);
          float tg = sigm_fast(accT[mt][nt][r] + tb);
          float sn = (hg - sp) * tg + sp;
          if (l < 2) *(float*)Sp = sn;
          else out[(size_t)(m0 + row) * DD + gc] = sn;
        }
      }
    }
    __syncthreads();   // S update visible before next layer's frag reads
  }
}

// ---------------------------------------------------------------------------
extern "C" void kernel_launch(void* const* d_in, const int* in_sizes, int n_in,
                              void* d_out, int out_size, void* d_ws, size_t ws_size,
                              hipStream_t stream) {
  const float* h0  = (const float*)d_in[0];
  const float* seq = (const float*)d_in[1];
  const float* wH  = (const float*)d_in[2];
  const float* bH  = (const float*)d_in[3];
  const float* wT  = (const float*)d_in[4];
  const float* bT  = (const float*)d_in[5];
  const float* rHw = (const float*)d_in[6];
  const float* rHb = (const float*)d_in[7];
  const float* rTw = (const float*)d_in[8];
  const float* rTb = (const float*)d_in[9];
  float* out = (float*)d_out;

  char* ws = (char*)d_ws;
  float* noise_i = (float*)(ws);                       // 64 KB
  float* noise_s = (float*)(ws + (64 << 10));          // 64 KB
  float* vH0     = (float*)(ws + (128 << 10));         // 64 KB
  float* vT0     = (float*)(ws + (192 << 10));         // 64 KB
  u16* Wt    = (u16*)(ws + (256 << 10));               // 6 x 512 KB

  noise_kernel<<<64, 256, 0, stream>>>(noise_i, noise_s);
  vec0_kernel<<<64, 256, 0, stream>>>(h0, noise_s, rHw, rHb, rTw, rTb, vH0, vT0);
  wt_all<<<384, 256, 0, stream>>>(wH, wT, rHw, rTw, Wt);

  fused_rhn<<<M_TOT / BM, 512, 0, stream>>>(
      seq, Wt, noise_i, noise_s, vH0, vT0, h0, bH, bT, rHb, rTb, out);
}

// Round 6
// 1005.505 us; speedup vs baseline: 1.3143x; 1.3143x over previous
//
#include <hip/hip_runtime.h>
#include <stdint.h>
#include <math.h>

// Problem constants (fixed by reference setup_inputs)
#define B_SZ   32
#define T_LEN  2048
#define DIN    512
#define DD     512
#define M_TOT  (B_SZ * T_LEN)   // 65536 rows
#define BM     64               // fused-kernel row tile
#define WSZ    ((size_t)DD * DD)

typedef unsigned short u16;
typedef __attribute__((ext_vector_type(8))) short short8;
typedef __attribute__((ext_vector_type(4))) float f32x4;
typedef __attribute__((ext_vector_type(4))) unsigned int u32x4;

// ---------------------------------------------------------------------------
// fp32 -> bf16 round-to-nearest-even (scalar, for wt_all)
// ---------------------------------------------------------------------------
__device__ __forceinline__ u16 f2bf(float f) {
  uint32_t u = __float_as_uint(f);
  uint32_t r = (u + 0x7FFFu + ((u >> 16) & 1u)) >> 16;
  return (u16)r;
}

// packed f32x2 -> bf16x2 (RTNE), gfx950 hw instruction (no builtin)
__device__ __forceinline__ uint32_t cvtpk(float lo, float hi) {
  uint32_t r;
  asm("v_cvt_pk_bf16_f32 %0, %1, %2" : "=v"(r) : "v"(lo), "v"(hi));
  return r;
}

// async global->LDS, 16B per lane
typedef const void __attribute__((address_space(1)))* as1cp;
typedef void __attribute__((address_space(3)))* as3p;
__device__ __forceinline__ void async16(const void* g, void* l) {
  __builtin_amdgcn_global_load_lds((as1cp)(uintptr_t)g,
                                   (as3p)(uint32_t)(uintptr_t)l, 16, 0, 0);
}

__device__ __forceinline__ float sigm_fast(float x) {
  return 1.f / (1.f + __expf(-x));
}
__device__ __forceinline__ float tanh_fast(float x) {
  return 1.f - 2.f / (1.f + __expf(2.f * x));
}

// ---------------------------------------------------------------------------
// Threefry-2x32 (20 rounds), bit-exact vs JAX's threefry2x32 primitive.
// ---------------------------------------------------------------------------
__device__ __forceinline__ uint32_t rotl32(uint32_t x, int n) {
  return (x << n) | (x >> (32 - n));
}

__device__ __forceinline__ void threefry2x32(uint32_t k0, uint32_t k1,
                                             uint32_t x0, uint32_t x1,
                                             uint32_t& o0, uint32_t& o1) {
  const uint32_t ks0 = k0, ks1 = k1, ks2 = k0 ^ k1 ^ 0x1BD11BDAu;
  uint32_t v0 = x0 + ks0, v1 = x1 + ks1;
#define TF_R(r) { v0 += v1; v1 = rotl32(v1, (r)); v1 ^= v0; }
  TF_R(13) TF_R(15) TF_R(26) TF_R(6)
  v0 += ks1; v1 += ks2 + 1u;
  TF_R(17) TF_R(29) TF_R(16) TF_R(24)
  v0 += ks2; v1 += ks0 + 2u;
  TF_R(13) TF_R(15) TF_R(26) TF_R(6)
  v0 += ks0; v1 += ks1 + 3u;
  TF_R(17) TF_R(29) TF_R(16) TF_R(24)
  v0 += ks1; v1 += ks2 + 4u;
  TF_R(13) TF_R(15) TF_R(26) TF_R(6)
  v0 += ks2; v1 += ks0 + 5u;
#undef TF_R
  o0 = v0; o1 = v1;
}

// ---------------------------------------------------------------------------
// Noise under JAX_ENABLE_X64=1 + partitionable threefry (verified round 3):
//   split (foldlike): keys[j] = threefry(key, (0, j))
//   bernoulli(p: python float -> f64): 64-bit draw bits64[i]=(b1<<32)|b2,
//   counter (0,i); u<0.25 <=> b1<0x40000000 ; u<0.75 <=> b1<0xC0000000
// ---------------------------------------------------------------------------
__global__ void noise_kernel(float* __restrict__ noise_i, float* __restrict__ noise_s) {
  int i = blockIdx.x * blockDim.x + threadIdx.x;
  if (i >= B_SZ * DIN) return;
  uint32_t k1a, k1b, k2a, k2b;
  threefry2x32(0u, 42u, 0u, 0u, k1a, k1b);
  threefry2x32(0u, 42u, 0u, 1u, k2a, k2b);
  uint32_t b1, b2;
  threefry2x32(k1a, k1b, 0u, (uint32_t)i, b1, b2);
  noise_i[i] = (b1 < 0x40000000u) ? 4.0f : 0.0f;
  threefry2x32(k2a, k2b, 0u, (uint32_t)i, b1, b2);
  noise_s[i] = (b1 < 0xC0000000u) ? (1.0f / 0.75f) : 0.0f;
}

// layer-0 state projections, exact fp32 (t-independent)
__global__ __launch_bounds__(256) void vec0_kernel(
    const float* __restrict__ h0, const float* __restrict__ noise_s,
    const float* __restrict__ rHw, const float* __restrict__ rHb,
    const float* __restrict__ rTw, const float* __restrict__ rTb,
    float* __restrict__ vH0, float* __restrict__ vT0) {
  __shared__ float sdv[DD];
  const int b = blockIdx.x >> 1;
  const int c = (blockIdx.x & 1) * 256 + threadIdx.x;
  for (int k = threadIdx.x; k < DD; k += 256)
    sdv[k] = h0[k] * noise_s[b * DD + k];
  __syncthreads();
  float aH = 0.f, aT = 0.f;
  for (int k = 0; k < DD; ++k) {
    float v = sdv[k];
    aH += v * rHw[(size_t)k * DD + c];
    aT += v * rTw[(size_t)k * DD + c];
  }
  vH0[b * DD + c] = aH + rHb[c];
  vT0[b * DD + c] = aT + rTb[c];
}

// ---------------------------------------------------------------------------
// Transpose+convert all six 512x512 fp32 W[k][n] -> bf16 Wt[n][k].
// Wt order: 0=wH 1=wT 2=r1H 3=r1T 4=r2H 5=r2T
// ---------------------------------------------------------------------------
__global__ __launch_bounds__(256) void wt_all(
    const float* __restrict__ wH, const float* __restrict__ wT,
    const float* __restrict__ rHw, const float* __restrict__ rTw,
    u16* __restrict__ Wt) {
  __shared__ float tile[64][68];
  const int which = blockIdx.x >> 6;
  const float* W;
  switch (which) {
    case 0: W = wH; break;
    case 1: W = wT; break;
    case 2: W = rHw + WSZ; break;
    case 3: W = rTw + WSZ; break;
    case 4: W = rHw + 2 * WSZ; break;
    default: W = rTw + 2 * WSZ; break;
  }
  u16* dst = Wt + (size_t)which * WSZ;
  const int tb = blockIdx.x & 63;
  const int kt = (tb >> 3) * 64;
  const int nt = (tb & 7) * 64;
  const int tid = threadIdx.x;
  {
    int r = tid >> 2;
#pragma unroll
    for (int u = 0; u < 4; ++u) {
      int c = ((tid & 3) + u * 4) * 4;
      float4 v = *(const float4*)(W + (size_t)(kt + r) * DD + nt + c);
      tile[r][c] = v.x; tile[r][c + 1] = v.y; tile[r][c + 2] = v.z; tile[r][c + 3] = v.w;
    }
  }
  __syncthreads();
  {
    int n = tid >> 2, seg = (tid & 3) * 16;
    u16 o[16];
#pragma unroll
    for (int u = 0; u < 16; ++u) o[u] = f2bf(tile[seg + u][n]);
    *(uint4*)(dst + (size_t)(nt + n) * DD + kt + seg) = *(const uint4*)o;
    *(uint4*)(dst + (size_t)(nt + n) * DD + kt + seg + 8) = *(const uint4*)(o + 8);
  }
}

// ---------------------------------------------------------------------------
// FUSED 3-LAYER RHN kernel, v2.
// Identical structure to round 5 EXCEPT the K-loop: the W-fragment
// ping-pong banks are now NAMED variables selected by macro token-pasting
// (whA/whB, wtA/wtB) -> every register index is compile-time static
// regardless of unrolling decisions. Round 5's wh[cur][nt] (runtime cur)
// was allocated in scratch (rule #20): 1.49 GB HBM r/w spill traffic.
// ---------------------------------------------------------------------------
__global__ __launch_bounds__(512, 2) void fused_rhn(
    const float* __restrict__ seq,   // [65536][512] f32
    const u16* __restrict__ Wt,      // 6 x [512n][512k] bf16
    const float* __restrict__ noise_i,  // [32][512]
    const float* __restrict__ noise_s,  // [32][512]
    const float* __restrict__ vH0,   // [32][512]
    const float* __restrict__ vT0,
    const float* __restrict__ h0,    // [512]
    const float* __restrict__ bH, const float* __restrict__ bT,
    const float* __restrict__ rHb, const float* __restrict__ rTb,
    float* __restrict__ out) {
  __shared__ float S[BM * DD];       // 128 KB, swizzled f32 state tile
  __shared__ float nzi[DD];
  __shared__ float nzs[DD];

  const int tid  = threadIdx.x;      // 0..511
  const int lane = tid & 63, wid = tid >> 6;
  const int m0   = blockIdx.x * BM;
  const int bidx = m0 >> 11;         // batch index (64 | 2048)
  const int q  = lane >> 4, mr = lane & 15;
  const int c0w = wid * 64;          // wave's column base
  const int swm = (mr & 7) << 4;     // frag-read swizzle (row&7 == mr&7)

  // stage noise rows for this batch
  if (tid < DD) {
    nzi[tid] = noise_i[bidx * DD + tid];
    nzs[tid] = noise_s[bidx * DD + tid];
  }
  // stage seq tile as layer-0 A/state: linear LDS dest, pre-swizzled source.
  // granule g: row = g>>7, slot = g&127 holds source k16 = slot ^ (row&7).
#pragma unroll
  for (int t = 0; t < 16; ++t) {
    int g = tid + t * 512;
    int row = g >> 7, slot = g & 127;
    int j16 = slot ^ (row & 7);
    async16(seq + (size_t)(m0 + row) * DD + j16 * 4, (char*)S + (size_t)g * 16);
  }
  __syncthreads();   // drains vmcnt (compiler emits vmcnt(0) before barrier)

  for (int l = 0; l < 3; ++l) {
    const u16* WH = Wt + (size_t)(2 * l) * WSZ;
    const u16* WTm = WH + WSZ;
    const float* nz = (l == 0) ? nzi : nzs;

    f32x4 accH[4][4], accT[4][4];
#pragma unroll
    for (int i = 0; i < 4; ++i)
#pragma unroll
      for (int j = 0; j < 4; ++j) {
        accH[i][j] = (f32x4){0.f, 0.f, 0.f, 0.f};
        accT[i][j] = (f32x4){0.f, 0.f, 0.f, 0.f};
      }

    // Named two-bank W fragment ping-pong (static registers by construction)
    short8 whA[4], wtA[4], whB[4], wtB[4];
    size_t cobase[4];
#pragma unroll
    for (int nt = 0; nt < 4; ++nt)
      cobase[nt] = (size_t)(c0w + nt * 16 + mr) * DD + q * 8;

#define PF_LOAD(BANK, KB1) do {                                  \
    _Pragma("unroll")                                            \
    for (int nt = 0; nt < 4; ++nt) {                             \
      const size_t co_ = cobase[nt] + (size_t)(KB1) * 32;        \
      wh##BANK[nt] = *(const short8*)(WH + co_);                 \
      wt##BANK[nt] = *(const short8*)(WTm + co_);                \
    } } while (0)

#define COMPUTE(BANK, KB) do {                                   \
    const int k0_ = (KB) * 32 + q * 8;                           \
    const float4 n0_ = *(const float4*)&nz[k0_];                 \
    const float4 n1_ = *(const float4*)&nz[k0_ + 4];             \
    short8 a_[4];                                                \
    _Pragma("unroll")                                            \
    for (int mt = 0; mt < 4; ++mt) {                             \
      const int row_ = mt * 16 + mr;                             \
      const char* Sb_ = (const char*)S + (size_t)row_ * 2048;    \
      const int kbase_ = (KB) * 128 + q * 32;                    \
      float4 v0_ = *(const float4*)(Sb_ + (kbase_ ^ swm));       \
      float4 v1_ = *(const float4*)(Sb_ + ((kbase_ + 16) ^ swm));\
      u32x4 pk_;                                                 \
      pk_.x = cvtpk(v0_.x * n0_.x, v0_.y * n0_.y);               \
      pk_.y = cvtpk(v0_.z * n0_.z, v0_.w * n0_.w);               \
      pk_.z = cvtpk(v1_.x * n1_.x, v1_.y * n1_.y);               \
      pk_.w = cvtpk(v1_.z * n1_.z, v1_.w * n1_.w);               \
      a_[mt] = *(short8*)&pk_;                                   \
    }                                                            \
    _Pragma("unroll")                                            \
    for (int nt = 0; nt < 4; ++nt) {                             \
      _Pragma("unroll")                                          \
      for (int mt = 0; mt < 4; ++mt) {                           \
        accH[mt][nt] = __builtin_amdgcn_mfma_f32_16x16x32_bf16(a_[mt], wh##BANK[nt], accH[mt][nt], 0, 0, 0); \
        accT[mt][nt] = __builtin_amdgcn_mfma_f32_16x16x32_bf16(a_[mt], wt##BANK[nt], accT[mt][nt], 0, 0, 0); \
      }                                                          \
    } } while (0)

    PF_LOAD(A, 0);
    for (int kb2 = 0; kb2 < 7; ++kb2) {
      const int kb = kb2 * 2;
      PF_LOAD(B, kb + 1);
      COMPUTE(A, kb);
      PF_LOAD(A, kb + 2);
      COMPUTE(B, kb + 1);
    }
    PF_LOAD(B, 15);
    COMPUTE(A, 14);
    COMPUTE(B, 15);
#undef PF_LOAD
#undef COMPUTE

    // all waves done reading S before we overwrite it
    __syncthreads();

    const float* hbv = (l == 0) ? bH : (rHb + l * DD);
    const float* tbv = (l == 0) ? bT : (rTb + l * DD);
    const int b512 = bidx * DD;
#pragma unroll
    for (int nt = 0; nt < 4; ++nt) {
      const int gc = c0w + nt * 16 + mr;
      float hb = hbv[gc], tb = tbv[gc];
      float h0c = 0.f;
      if (l == 0) {
        hb += vH0[b512 + gc];
        tb += vT0[b512 + gc];
        h0c = h0[gc];
      }
#pragma unroll
      for (int mt = 0; mt < 4; ++mt) {
#pragma unroll
        for (int r = 0; r < 4; ++r) {
          const int row = mt * 16 + q * 4 + r;
          char* Sp = (char*)S + (size_t)row * 2048 + (((unsigned)(gc * 4)) ^ ((row & 7) << 4));
          float sp = (l == 0) ? h0c : *(const float*)Sp;
          float hg = tanh_fast(accH[mt][nt][r] + hb);
          float tg = sigm_fast(accT[mt][nt][r] + tb);
          float sn = (hg - sp) * tg + sp;
          if (l < 2) *(float*)Sp = sn;
          else out[(size_t)(m0 + row) * DD + gc] = sn;
        }
      }
    }
    __syncthreads();   // S update visible before next layer's frag reads
  }
}

// ---------------------------------------------------------------------------
extern "C" void kernel_launch(void* const* d_in, const int* in_sizes, int n_in,
                              void* d_out, int out_size, void* d_ws, size_t ws_size,
                              hipStream_t stream) {
  const float* h0  = (const float*)d_in[0];
  const float* seq = (const float*)d_in[1];
  const float* wH  = (const float*)d_in[2];
  const float* bH  = (const float*)d_in[3];
  const float* wT  = (const float*)d_in[4];
  const float* bT  = (const float*)d_in[5];
  const float* rHw = (const float*)d_in[6];
  const float* rHb = (const float*)d_in[7];
  const float* rTw = (const float*)d_in[8];
  const float* rTb = (const float*)d_in[9];
  float* out = (float*)d_out;

  char* ws = (char*)d_ws;
  float* noise_i = (float*)(ws);                       // 64 KB
  float* noise_s = (float*)(ws + (64 << 10));          // 64 KB
  float* vH0     = (float*)(ws + (128 << 10));         // 64 KB
  float* vT0     = (float*)(ws + (192 << 10));         // 64 KB
  u16* Wt    = (u16*)(ws + (256 << 10));               // 6 x 512 KB

  noise_kernel<<<64, 256, 0, stream>>>(noise_i, noise_s);
  vec0_kernel<<<64, 256, 0, stream>>>(h0, noise_s, rHw, rHb, rTw, rTb, vH0, vT0);
  wt_all<<<384, 256, 0, stream>>>(wH, wT, rHw, rTw, Wt);

  fused_rhn<<<M_TOT / BM, 512, 0, stream>>>(
      seq, Wt, noise_i, noise_s, vH0, vT0, h0, bH, bT, rHb, rTb, out);
}